// Round 1
// baseline (349.000 us; speedup 1.0000x reference)
//
#include <hip/hip_runtime.h>
#include <stdint.h>

// E=512, H=8, D=64, B=4, Nq=Nk=2048
// bf16 MFMA pipeline: cvt -> QKV proj GEMM -> flash attn (masked) -> out proj GEMM

typedef __attribute__((ext_vector_type(8))) short bf16x8;  // 8 bf16 in 4 VGPRs
typedef __attribute__((ext_vector_type(4))) float f32x4;

#define LOG2E 1.4426950408889634f

static __device__ __forceinline__ unsigned short f2bf(float f) {
    union { float f; unsigned u; } x; x.f = f;
    unsigned r = x.u + 0x7fffu + ((x.u >> 16) & 1u);  // RTN-even
    return (unsigned short)(r >> 16);
}

static __device__ __forceinline__ f32x4 mfma16(bf16x8 a, bf16x8 b, f32x4 c) {
    return __builtin_amdgcn_mfma_f32_16x16x32_bf16(a, b, c, 0, 0, 0);
}

#define GLOAD_LDS16(g, l)                                                            \
    __builtin_amdgcn_global_load_lds((const __attribute__((address_space(1))) void*)(g), \
                                     (__attribute__((address_space(3))) void*)(l), 16, 0, 0)

// ---------------- conversion kernels ----------------

// fp32 -> bf16, 4 elems/thread. grid (1048576/256, 3)
__global__ __launch_bounds__(256) void cvt_x_kernel(
    const float* __restrict__ xq, const float* __restrict__ xk, const float* __restrict__ xv,
    short* __restrict__ oq, short* __restrict__ ok, short* __restrict__ ov)
{
    const float* src = (blockIdx.y == 0) ? xq : (blockIdx.y == 1) ? xk : xv;
    short* dst = (blockIdx.y == 0) ? oq : (blockIdx.y == 1) ? ok : ov;
    size_t i = (size_t)blockIdx.x * 256 + threadIdx.x;
    float4 v = ((const float4*)src)[i];
    short4 o;
    o.x = (short)f2bf(v.x); o.y = (short)f2bf(v.y);
    o.z = (short)f2bf(v.z); o.w = (short)f2bf(v.w);
    ((short4*)dst)[i] = o;
}

// W[k][n] fp32 -> WT[n][k] bf16 (transposed so GEMM B-frag reads are contiguous)
// grid (128, 4): t -> n = t&511, k0 = (t>>9)*8
__global__ __launch_bounds__(256) void cvt_wt_kernel(
    const float* __restrict__ Wq, const float* __restrict__ Wk,
    const float* __restrict__ Wv, const float* __restrict__ Wo,
    short* __restrict__ WqT, short* __restrict__ WkT,
    short* __restrict__ WvT, short* __restrict__ WoT)
{
    int z = blockIdx.y;
    const float* W = (z == 0) ? Wq : (z == 1) ? Wk : (z == 2) ? Wv : Wo;
    short* WT = (z == 0) ? WqT : (z == 1) ? WkT : (z == 2) ? WvT : WoT;
    int t = blockIdx.x * 256 + threadIdx.x;
    int n = t & 511;
    int k0 = (t >> 9) * 8;
    union { short s[8]; int4 v; } u;
#pragma unroll
    for (int j = 0; j < 8; ++j) u.s[j] = (short)f2bf(W[(size_t)(k0 + j) * 512 + n]);
    *(int4*)(WT + (size_t)n * 512 + k0) = u.v;
}

// mask (4-byte elems, nonzero = keep) -> packed bits. word w of row covers k=[w*64,w*64+64)
// grid 2048 blocks x 256: wave per row-quarter... each wave does one row (4 waves/block)
__global__ __launch_bounds__(256) void pack_mask_kernel(
    const int* __restrict__ mask, unsigned long long* __restrict__ mp)
{
    int lane = threadIdx.x & 63;
    int row = blockIdx.x * 4 + (threadIdx.x >> 6);  // b*2048+q, 0..8191
    const int* mrow = mask + (size_t)row * 2048;
#pragma unroll 4
    for (int w = 0; w < 32; ++w) {
        unsigned long long bits = __ballot(mrow[w * 64 + lane] != 0);
        if (lane == 0) mp[(size_t)row * 32 + w] = bits;
    }
}

// ---------------- GEMM: C[8192x512] = A[8192x512] @ W  (+bias) ----------------
// A bf16 row-major lda=512; BT = W^T bf16 [n][k] ldb=512.
// 128x128 tile, BK=64, 4 waves (2x2), wave = 64x64 (4x4 frags of 16x16x32).
// LDS staged via global_load_lds w=16; XOR-swizzle via pre-swizzled global src (rule #21).
// mode 0: Q -> [b,h,tok,d] bf16 ; 1: K same ; 2: V -> [b,h,d,tok] bf16 ; 3: fp32 row-major out
__global__ __launch_bounds__(256) void gemm_kernel(
    const short* __restrict__ A, const short* __restrict__ BT,
    const float* __restrict__ bias, void* __restrict__ Cout, int mode)
{
    __shared__ char lds[32768];
    const int tid = threadIdx.x;
    const int lane = tid & 63;
    const int wid = tid >> 6;
    const int l15 = lane & 15, l4 = lane >> 4;
    const int m0 = blockIdx.y * 128;
    const int n0 = blockIdx.x * 128;
    const int wr = wid >> 1, wc = wid & 1;

    f32x4 zero = {0.f, 0.f, 0.f, 0.f};
    f32x4 acc[4][4];
#pragma unroll
    for (int i = 0; i < 4; ++i)
#pragma unroll
        for (int j = 0; j < 4; ++j) acc[i][j] = zero;

    char* Alds = lds;
    char* Blds = lds + 16384;

    for (int t = 0; t < 8; ++t) {
        const int k0 = t * 64;
        // stage 128x64 bf16 tiles; LDS linear, global src pre-swizzled: chunk c holds
        // global k-chunk (c ^ (r&7)); 4 shots x 256 thr x 16B per tile
#pragma unroll
        for (int s = 0; s < 4; ++s) {
            int p = s * 256 + tid;
            int r = p >> 3, c = p & 7;
            GLOAD_LDS16(A + (size_t)(m0 + r) * 512 + k0 + 8 * (c ^ (r & 7)),
                        Alds + s * 4096 + wid * 1024);
            GLOAD_LDS16(BT + (size_t)(n0 + r) * 512 + k0 + 8 * (c ^ (r & 7)),
                        Blds + s * 4096 + wid * 1024);
        }
        __syncthreads();
#pragma unroll
        for (int ks = 0; ks < 2; ++ks) {
            bf16x8 af[4], bfr[4];
#pragma unroll
            for (int mb = 0; mb < 4; ++mb) {
                int row = wr * 64 + mb * 16 + l15;
                af[mb] = *(const bf16x8*)(Alds + row * 128 +
                                          ((ks * 64 + l4 * 16) ^ ((row & 7) << 4)));
            }
#pragma unroll
            for (int nb = 0; nb < 4; ++nb) {
                int row = wc * 64 + nb * 16 + l15;
                bfr[nb] = *(const bf16x8*)(Blds + row * 128 +
                                           ((ks * 64 + l4 * 16) ^ ((row & 7) << 4)));
            }
#pragma unroll
            for (int mb = 0; mb < 4; ++mb)
#pragma unroll
                for (int nb = 0; nb < 4; ++nb)
                    acc[mb][nb] = mfma16(af[mb], bfr[nb], acc[mb][nb]);
        }
        __syncthreads();
    }

    // epilogue: D layout col=lane&15, row=(lane>>4)*4+reg [measured m89/m91]
#pragma unroll
    for (int nb = 0; nb < 4; ++nb) {
        int n = n0 + wc * 64 + nb * 16 + l15;
        float bv = bias[n];
#pragma unroll
        for (int mb = 0; mb < 4; ++mb) {
#pragma unroll
            for (int r = 0; r < 4; ++r) {
                int m = m0 + wr * 64 + mb * 16 + l4 * 4 + r;
                float val = acc[mb][nb][r] + bv;
                if (mode == 3) {
                    ((float*)Cout)[(size_t)m * 512 + n] = val;
                } else {
                    int b = m >> 11, tok = m & 2047;
                    int h = n >> 6, d = n & 63;
                    short* o = (short*)Cout;
                    if (mode == 2)
                        o[((size_t)(b * 8 + h) * 64 + d) * 2048 + tok] = (short)f2bf(val);
                    else
                        o[((size_t)(b * 8 + h) * 2048 + tok) * 64 + d] = (short)f2bf(val);
                }
            }
        }
    }
}

// ---------------- masked flash attention ----------------
// grid (32, 8, 4) = (q-tile, h, b); 4 waves, wave owns 16 q-rows; KVBLK=64.
// Q:[b,h,q,d] K:[b,h,k,d] VT:[b,h,d,k] all bf16; mp packed mask bits; O:[b,q,h*64+d] bf16
__global__ __launch_bounds__(256) void attn_kernel(
    const short* __restrict__ Q, const short* __restrict__ K,
    const short* __restrict__ VT, const unsigned long long* __restrict__ mp,
    short* __restrict__ O)
{
    __shared__ short Plds[4][1024];  // per-wave 16x64 bf16 P buffer (XOR-swizzled)
    const int lane = threadIdx.x & 63;
    const int wid = threadIdx.x >> 6;
    const int l15 = lane & 15, l4 = lane >> 4;
    const int b = blockIdx.z, h = blockIdx.y, qt = blockIdx.x;
    const int q0 = qt * 64 + wid * 16;
    const size_t bh = (size_t)b * 8 + h;
    const short* Qp = Q + (bh * 2048 + q0) * 64;
    const short* Kp0 = K + bh * 2048 * 64;
    const short* Vp = VT + bh * 64 * 2048;
    char* Pw = (char*)&Plds[wid][0];

    // A-frag of Q: row=lane&15, k=(lane>>4)*8+j (+32 for second K-step)
    bf16x8 aq0 = *(const bf16x8*)(Qp + l15 * 64 + l4 * 8);
    bf16x8 aq1 = *(const bf16x8*)(Qp + l15 * 64 + l4 * 8 + 32);

    f32x4 zero = {0.f, 0.f, 0.f, 0.f};
    f32x4 o[4];  // 4 d-blocks of O[16q x 64d]
    float mrun[4], lrun[4];
#pragma unroll
    for (int r = 0; r < 4; ++r) { o[r] = zero; mrun[r] = -1e30f; lrun[r] = 0.f; }

    const unsigned long long* mpr[4];
#pragma unroll
    for (int r = 0; r < 4; ++r)
        mpr[r] = mp + ((size_t)b * 2048 + (q0 + l4 * 4 + r)) * 32;

    for (int kt = 0; kt < 32; ++kt) {
        const short* Kp = Kp0 + (size_t)kt * 64 * 64;
        // S[16q x 64k]: 4 col-frags; B-frag of K^T: lane holds K[c*16+(lane&15)][(lane>>4)*8+j]
        f32x4 s[4];
#pragma unroll
        for (int c = 0; c < 4; ++c) {
            const short* kr = Kp + (c * 16 + l15) * 64 + l4 * 8;
            bf16x8 bk0 = *(const bf16x8*)(kr);
            bf16x8 bk1 = *(const bf16x8*)(kr + 32);
            s[c] = mfma16(aq1, bk1, mfma16(aq0, bk0, zero));
        }
        unsigned long long mw[4];
#pragma unroll
        for (int r = 0; r < 4; ++r) mw[r] = mpr[r][kt];

        // mask + scale; -1e30 sentinel self-corrects for all-masked prefixes
        float p[4][4];
        float tmax[4] = {-1e30f, -1e30f, -1e30f, -1e30f};
#pragma unroll
        for (int c = 0; c < 4; ++c) {
            int kcol = c * 16 + l15;
#pragma unroll
            for (int r = 0; r < 4; ++r) {
                float sv = ((mw[r] >> kcol) & 1ull) ? s[c][r] * 0.125f : -1e30f;
                p[c][r] = sv;
                tmax[r] = fmaxf(tmax[r], sv);
            }
        }
        // row reductions across the 16-lane col group (rows fixed per lane>>4)
#pragma unroll
        for (int off = 1; off < 16; off <<= 1)
#pragma unroll
            for (int r = 0; r < 4; ++r)
                tmax[r] = fmaxf(tmax[r], __shfl_xor(tmax[r], off, 64));

        float alpha[4], lsum[4] = {0.f, 0.f, 0.f, 0.f};
#pragma unroll
        for (int r = 0; r < 4; ++r) {
            float mnew = fmaxf(mrun[r], tmax[r]);
            alpha[r] = exp2f((mrun[r] - mnew) * LOG2E);
            mrun[r] = mnew;
        }
        // P = exp(s - m), write bf16 to swizzled P_lds (byte = q*128 + (2k ^ ((q&7)<<4)))
#pragma unroll
        for (int c = 0; c < 4; ++c) {
            int col2 = (c * 16 + l15) * 2;
#pragma unroll
            for (int r = 0; r < 4; ++r) {
                float e = exp2f((p[c][r] - mrun[r]) * LOG2E);
                lsum[r] += e;
                int ql = l4 * 4 + r;
                *(short*)(Pw + ql * 128 + (col2 ^ ((ql & 7) << 4))) = (short)f2bf(e);
            }
        }
#pragma unroll
        for (int off = 1; off < 16; off <<= 1)
#pragma unroll
            for (int r = 0; r < 4; ++r)
                lsum[r] += __shfl_xor(lsum[r], off, 64);
#pragma unroll
        for (int r = 0; r < 4; ++r) lrun[r] = lrun[r] * alpha[r] + lsum[r];
#pragma unroll
        for (int nb = 0; nb < 4; ++nb)
#pragma unroll
            for (int r = 0; r < 4; ++r) o[nb][r] *= alpha[r];

        asm volatile("s_waitcnt lgkmcnt(0)" ::: "memory");  // P writes visible to own wave

        // PV: A-frag = P rows (lane&15), k=(lane>>4)*8 + ss*32; B-frag = VT rows contiguous
#pragma unroll
        for (int ss = 0; ss < 2; ++ss) {
            bf16x8 ap = *(const bf16x8*)(Pw + l15 * 128 +
                                         ((l4 * 16 + ss * 64) ^ ((l15 & 7) << 4)));
            const short* vb = Vp + (size_t)l15 * 2048 + kt * 64 + l4 * 8 + ss * 32;
#pragma unroll
            for (int nb = 0; nb < 4; ++nb) {
                bf16x8 bv = *(const bf16x8*)(vb + (size_t)nb * 16 * 2048);
                o[nb] = mfma16(ap, bv, o[nb]);
            }
        }
    }

#pragma unroll
    for (int r = 0; r < 4; ++r) {
        float rl = 1.0f / lrun[r];
        int q = q0 + l4 * 4 + r;
        size_t base = ((size_t)b * 2048 + q) * 512 + h * 64;
#pragma unroll
        for (int nb = 0; nb < 4; ++nb)
            O[base + nb * 16 + l15] = (short)f2bf(o[nb][r] * rl);
    }
}

// ---------------- launcher ----------------
extern "C" void kernel_launch(void* const* d_in, const int* in_sizes, int n_in,
                              void* d_out, int out_size, void* d_ws, size_t ws_size,
                              hipStream_t stream) {
    const float* q  = (const float*)d_in[0];
    const float* k  = (const float*)d_in[1];
    const float* v  = (const float*)d_in[2];
    const int*   gm = (const int*)d_in[3];     // 4-byte mask elems (int32/float32 both ok)
    const float* Wq = (const float*)d_in[4];  const float* bq = (const float*)d_in[5];
    const float* Wk = (const float*)d_in[6];  const float* bk = (const float*)d_in[7];
    const float* Wv = (const float*)d_in[8];  const float* bv = (const float*)d_in[9];
    const float* Wo = (const float*)d_in[10]; const float* bo = (const float*)d_in[11];

    char* ws = (char*)d_ws;
    short* Xq  = (short*)(ws + 0);           // 8192x512 bf16 = 8 MiB each
    short* Xk  = (short*)(ws + 8388608);
    short* Xv  = (short*)(ws + 16777216);
    short* WqT = (short*)(ws + 25165824);    // 512x512 bf16 = 512 KiB each
    short* WkT = (short*)(ws + 25690112);
    short* WvT = (short*)(ws + 26214400);
    short* WoT = (short*)(ws + 26738688);
    short* Qw  = (short*)(ws + 27262976);    // [b,h,tok,d]
    short* Kw  = (short*)(ws + 35651584);    // [b,h,tok,d]
    short* VTw = (short*)(ws + 44040192);    // [b,h,d,tok]
    short* AO  = (short*)(ws + 52428800);    // attn out [b,tok,h*64+d]
    unsigned long long* MP = (unsigned long long*)(ws + 60817408);  // 2 MiB packed mask

    cvt_x_kernel<<<dim3(4096, 3), 256, 0, stream>>>(q, k, v, Xq, Xk, Xv);
    cvt_wt_kernel<<<dim3(128, 4), 256, 0, stream>>>(Wq, Wk, Wv, Wo, WqT, WkT, WvT, WoT);
    pack_mask_kernel<<<dim3(2048), 256, 0, stream>>>(gm, MP);

    gemm_kernel<<<dim3(4, 64), 256, 0, stream>>>(Xq, WqT, bq, Qw, 0);
    gemm_kernel<<<dim3(4, 64), 256, 0, stream>>>(Xk, WkT, bk, Kw, 1);
    gemm_kernel<<<dim3(4, 64), 256, 0, stream>>>(Xv, WvT, bv, VTw, 2);

    attn_kernel<<<dim3(32, 8, 4), 256, 0, stream>>>(Qw, Kw, VTw, MP, AO);

    gemm_kernel<<<dim3(4, 64), 256, 0, stream>>>(AO, WoT, bo, (void*)d_out, 3);
}

// Round 2
// 237.938 us; speedup vs baseline: 1.4668x; 1.4668x over previous
//
#include <hip/hip_runtime.h>
#include <stdint.h>

// E=512, H=8, D=64, B=4, Nq=Nk=2048
// bf16 MFMA pipeline: cvt -> QKV proj GEMM -> flash attn (masked, swapped-QK^T) -> out proj GEMM

typedef __attribute__((ext_vector_type(8))) short bf16x8;  // 8 bf16 in 4 VGPRs
typedef __attribute__((ext_vector_type(4))) float f32x4;

#define LOG2E 1.4426950408889634f
#define SCL 0.18033688011112042f  // 0.125 * log2(e): softmax done in exp2 domain

static __device__ __forceinline__ unsigned short f2bf(float f) {
    union { float f; unsigned u; } x; x.f = f;
    unsigned r = x.u + 0x7fffu + ((x.u >> 16) & 1u);  // RTN-even
    return (unsigned short)(r >> 16);
}

static __device__ __forceinline__ f32x4 mfma16(bf16x8 a, bf16x8 b, f32x4 c) {
    return __builtin_amdgcn_mfma_f32_16x16x32_bf16(a, b, c, 0, 0, 0);
}

#define GLOAD_LDS16(g, l)                                                            \
    __builtin_amdgcn_global_load_lds((const __attribute__((address_space(1))) void*)(g), \
                                     (__attribute__((address_space(3))) void*)(l), 16, 0, 0)

// ---------------- conversion kernels ----------------

__global__ __launch_bounds__(256) void cvt_x_kernel(
    const float* __restrict__ xq, const float* __restrict__ xk, const float* __restrict__ xv,
    short* __restrict__ oq, short* __restrict__ ok, short* __restrict__ ov)
{
    const float* src = (blockIdx.y == 0) ? xq : (blockIdx.y == 1) ? xk : xv;
    short* dst = (blockIdx.y == 0) ? oq : (blockIdx.y == 1) ? ok : ov;
    size_t i = (size_t)blockIdx.x * 256 + threadIdx.x;
    float4 v = ((const float4*)src)[i];
    short4 o;
    o.x = (short)f2bf(v.x); o.y = (short)f2bf(v.y);
    o.z = (short)f2bf(v.z); o.w = (short)f2bf(v.w);
    ((short4*)dst)[i] = o;
}

__global__ __launch_bounds__(256) void cvt_wt_kernel(
    const float* __restrict__ Wq, const float* __restrict__ Wk,
    const float* __restrict__ Wv, const float* __restrict__ Wo,
    short* __restrict__ WqT, short* __restrict__ WkT,
    short* __restrict__ WvT, short* __restrict__ WoT)
{
    int z = blockIdx.y;
    const float* W = (z == 0) ? Wq : (z == 1) ? Wk : (z == 2) ? Wv : Wo;
    short* WT = (z == 0) ? WqT : (z == 1) ? WkT : (z == 2) ? WvT : WoT;
    int t = blockIdx.x * 256 + threadIdx.x;
    int n = t & 511;
    int k0 = (t >> 9) * 8;
    union { short s[8]; int4 v; } u;
#pragma unroll
    for (int j = 0; j < 8; ++j) u.s[j] = (short)f2bf(W[(size_t)(k0 + j) * 512 + n]);
    *(int4*)(WT + (size_t)n * 512 + k0) = u.v;
}

// mask (4-byte elems, nonzero = keep) -> packed bits; word w covers k=[w*64,w*64+64)
__global__ __launch_bounds__(256) void pack_mask_kernel(
    const int* __restrict__ mask, unsigned long long* __restrict__ mp)
{
    int lane = threadIdx.x & 63;
    int row = blockIdx.x * 4 + (threadIdx.x >> 6);  // b*2048+q
    const int* mrow = mask + (size_t)row * 2048;
#pragma unroll 4
    for (int w = 0; w < 32; ++w) {
        unsigned long long bits = __ballot(mrow[w * 64 + lane] != 0);
        if (lane == 0) mp[(size_t)row * 32 + w] = bits;
    }
}

// ---------------- GEMM: C[8192x512] = A[8192x512] @ W  (+bias) ----------------
__global__ __launch_bounds__(256) void gemm_kernel(
    const short* __restrict__ A, const short* __restrict__ BT,
    const float* __restrict__ bias, void* __restrict__ Cout, int mode)
{
    __shared__ char lds[32768];
    const int tid = threadIdx.x;
    const int lane = tid & 63;
    const int wid = tid >> 6;
    const int l15 = lane & 15, l4 = lane >> 4;
    const int m0 = blockIdx.y * 128;
    const int n0 = blockIdx.x * 128;
    const int wr = wid >> 1, wc = wid & 1;

    f32x4 zero = {0.f, 0.f, 0.f, 0.f};
    f32x4 acc[4][4];
#pragma unroll
    for (int i = 0; i < 4; ++i)
#pragma unroll
        for (int j = 0; j < 4; ++j) acc[i][j] = zero;

    char* Alds = lds;
    char* Blds = lds + 16384;

    for (int t = 0; t < 8; ++t) {
        const int k0 = t * 64;
#pragma unroll
        for (int s = 0; s < 4; ++s) {
            int p = s * 256 + tid;
            int r = p >> 3, c = p & 7;
            GLOAD_LDS16(A + (size_t)(m0 + r) * 512 + k0 + 8 * (c ^ (r & 7)),
                        Alds + s * 4096 + wid * 1024);
            GLOAD_LDS16(BT + (size_t)(n0 + r) * 512 + k0 + 8 * (c ^ (r & 7)),
                        Blds + s * 4096 + wid * 1024);
        }
        __syncthreads();
#pragma unroll
        for (int ks = 0; ks < 2; ++ks) {
            bf16x8 af[4], bfr[4];
#pragma unroll
            for (int mb = 0; mb < 4; ++mb) {
                int row = wr * 64 + mb * 16 + l15;
                af[mb] = *(const bf16x8*)(Alds + row * 128 +
                                          ((ks * 64 + l4 * 16) ^ ((row & 7) << 4)));
            }
#pragma unroll
            for (int nb = 0; nb < 4; ++nb) {
                int row = wc * 64 + nb * 16 + l15;
                bfr[nb] = *(const bf16x8*)(Blds + row * 128 +
                                           ((ks * 64 + l4 * 16) ^ ((row & 7) << 4)));
            }
#pragma unroll
            for (int mb = 0; mb < 4; ++mb)
#pragma unroll
                for (int nb = 0; nb < 4; ++nb)
                    acc[mb][nb] = mfma16(af[mb], bfr[nb], acc[mb][nb]);
        }
        __syncthreads();
    }

#pragma unroll
    for (int nb = 0; nb < 4; ++nb) {
        int n = n0 + wc * 64 + nb * 16 + l15;
        float bv = bias[n];
#pragma unroll
        for (int mb = 0; mb < 4; ++mb) {
#pragma unroll
            for (int r = 0; r < 4; ++r) {
                int m = m0 + wr * 64 + mb * 16 + l4 * 4 + r;
                float val = acc[mb][nb][r] + bv;
                if (mode == 3) {
                    ((float*)Cout)[(size_t)m * 512 + n] = val;
                } else {
                    int b = m >> 11, tok = m & 2047;
                    int h = n >> 6, d = n & 63;
                    short* o = (short*)Cout;
                    if (mode == 2)
                        o[((size_t)(b * 8 + h) * 64 + d) * 2048 + tok] = (short)f2bf(val);
                    else
                        o[((size_t)(b * 8 + h) * 2048 + tok) * 64 + d] = (short)f2bf(val);
                }
            }
        }
    }
}

// ---------------- masked flash attention (swapped QK^T, in-lane softmax) ----------------
// grid (16, 8, 4); 4 waves, wave owns 32 q-rows (2 subtiles of 16), KVBLK=64.
// S^T = mfma(K-frag, Q-frag): col=l15=q, row=l4*4+r=k. Softmax over k is 15 in-lane
// fmax + 2 shfl_xor. P packed to bf16 pairs -> 8 ds_write_b64 into per-wave swizzled
// LDS; PV reads ds_read_b128 A-frags. K+mask reg-double-buffered (prefetch next tile);
// V issued at iter top (latency hides under QK^T+softmax). Defer-max THR=8 (T13).
__global__ __launch_bounds__(256, 2) void attn_kernel(
    const short* __restrict__ Q, const short* __restrict__ K,
    const short* __restrict__ VT, const unsigned long long* __restrict__ mp,
    short* __restrict__ O)
{
    __shared__ char Plds[4][4096];  // per-wave [2 qs][16 q][128 B]
    const int lane = threadIdx.x & 63;
    const int wid = threadIdx.x >> 6;
    const int l15 = lane & 15, l4 = lane >> 4;
    const int b = blockIdx.z, h = blockIdx.y;
    const int q0 = blockIdx.x * 128 + wid * 32;
    const size_t bh = (size_t)b * 8 + h;
    const short* Qp = Q + (bh * 2048 + q0) * 64;
    const short* Kp = K + bh * 2048 * 64;
    const short* Vp = VT + bh * 64 * 2048;
    char* Pw = &Plds[wid][0];
    const int sw = (l15 & 7) << 4;  // per-row XOR swizzle (G4)

    // Q fragments (persistent): aq[qs][ds] = Q[q0+qs*16+l15][ds*32 + l4*8 + j]
    bf16x8 aq[2][2];
#pragma unroll
    for (int qs = 0; qs < 2; ++qs)
#pragma unroll
        for (int ds = 0; ds < 2; ++ds)
            aq[qs][ds] = *(const bf16x8*)(Qp + (qs * 16 + l15) * 64 + ds * 32 + l4 * 8);

    const f32x4 zero = {0.f, 0.f, 0.f, 0.f};
    f32x4 o[2][4];
    float mrun[2] = {-1e30f, -1e30f}, lrun[2] = {0.f, 0.f};
#pragma unroll
    for (int qs = 0; qs < 2; ++qs)
#pragma unroll
        for (int dt = 0; dt < 4; ++dt) o[qs][dt] = zero;

    const unsigned long long* mrow0 = mp + ((size_t)b * 2048 + q0 + l15) * 32;
    const unsigned long long* mrow1 = mrow0 + 16 * 32;

    bf16x8 kf[2][4][2];          // double-buffered K frags
    unsigned long long mw[2][2]; // double-buffered mask words

    // prefetch tile 0
#pragma unroll
    for (int kb = 0; kb < 4; ++kb)
#pragma unroll
        for (int ds = 0; ds < 2; ++ds)
            kf[0][kb][ds] = *(const bf16x8*)(Kp + (kb * 16 + l15) * 64 + ds * 32 + l4 * 8);
    mw[0][0] = mrow0[0]; mw[0][1] = mrow1[0];

#define ATTN_STEP(KT, CUR, NXT)                                                          \
    {                                                                                    \
        const int kt_ = (KT);                                                            \
        /* V frags for this tile (consumed at PV; latency hidden) */                     \
        bf16x8 vf[4][2];                                                                 \
        _Pragma("unroll") for (int dt = 0; dt < 4; ++dt)                                 \
            _Pragma("unroll") for (int ks = 0; ks < 2; ++ks)                             \
                vf[dt][ks] = *(const bf16x8*)(Vp + (size_t)(dt * 16 + l15) * 2048 +      \
                                              kt_ * 64 + ks * 32 + l4 * 8);              \
        /* prefetch next K tile + mask */                                                \
        const int ktn_ = (kt_ + 1 < 32) ? kt_ + 1 : 31;                                  \
        _Pragma("unroll") for (int kb = 0; kb < 4; ++kb)                                 \
            _Pragma("unroll") for (int ds = 0; ds < 2; ++ds)                             \
                kf[NXT][kb][ds] = *(const bf16x8*)(Kp +                                  \
                    (size_t)(ktn_ * 64 + kb * 16 + l15) * 64 + ds * 32 + l4 * 8);        \
        mw[NXT][0] = mrow0[ktn_]; mw[NXT][1] = mrow1[ktn_];                              \
        /* QK^T -> S^T[k][q]: col=l15=q, row=l4*4+r = k (within kb*16) */                \
        f32x4 s[2][4];                                                                   \
        _Pragma("unroll") for (int qs = 0; qs < 2; ++qs)                                 \
            _Pragma("unroll") for (int kb = 0; kb < 4; ++kb) {                           \
                f32x4 t0 = mfma16(kf[CUR][kb][0], aq[qs][0], zero);                      \
                s[qs][kb] = mfma16(kf[CUR][kb][1], aq[qs][1], t0);                       \
            }                                                                            \
        /* mask + scale (exp2 domain), in-lane max + 2 shfl */                           \
        float pmax[2];                                                                   \
        _Pragma("unroll") for (int qs = 0; qs < 2; ++qs) {                               \
            unsigned long long mws = mw[CUR][qs] >> (l4 * 4);                            \
            unsigned w0 = (unsigned)mws, w1 = (unsigned)(mws >> 32);                     \
            float pm = -1e30f;                                                           \
            _Pragma("unroll") for (int kb = 0; kb < 4; ++kb) {                           \
                unsigned wsel = (kb & 2) ? w1 : w0;                                      \
                _Pragma("unroll") for (int r = 0; r < 4; ++r) {                          \
                    unsigned bit = 1u << (((kb & 1) << 4) + r);                          \
                    float sv = (wsel & bit) ? s[qs][kb][r] * SCL : -1e30f;               \
                    s[qs][kb][r] = sv;                                                   \
                    pm = fmaxf(pm, sv);                                                  \
                }                                                                        \
            }                                                                            \
            pm = fmaxf(pm, __shfl_xor(pm, 16, 64));                                      \
            pm = fmaxf(pm, __shfl_xor(pm, 32, 64));                                      \
            pmax[qs] = pm;                                                               \
        }                                                                                \
        /* defer-max: rescale only when a row max grew past THR=8 (log2 units) */        \
        int need = (pmax[0] > mrun[0] + 8.f) | (pmax[1] > mrun[1] + 8.f);                \
        if (__any(need)) {                                                               \
            _Pragma("unroll") for (int qs = 0; qs < 2; ++qs) {                           \
                float mnew = fmaxf(mrun[qs], pmax[qs]);                                  \
                float al = exp2f(mrun[qs] - mnew);                                       \
                mrun[qs] = mnew;                                                         \
                lrun[qs] *= al;                                                          \
                _Pragma("unroll") for (int r = 0; r < 4; ++r) {                          \
                    float aR = __shfl(al, l4 * 4 + r, 64);                               \
                    _Pragma("unroll") for (int dt = 0; dt < 4; ++dt)                     \
                        o[qs][dt][r] *= aR;                                              \
                }                                                                        \
            }                                                                            \
        }                                                                                \
        /* exp, sum, pack pairs, write swizzled P_lds */                                 \
        _Pragma("unroll") for (int qs = 0; qs < 2; ++qs) {                               \
            float ls = 0.f;                                                              \
            unsigned pk[8];                                                              \
            _Pragma("unroll") for (int kb = 0; kb < 4; ++kb) {                           \
                float e0 = exp2f(s[qs][kb][0] - mrun[qs]);                               \
                float e1 = exp2f(s[qs][kb][1] - mrun[qs]);                               \
                float e2 = exp2f(s[qs][kb][2] - mrun[qs]);                               \
                float e3 = exp2f(s[qs][kb][3] - mrun[qs]);                               \
                ls += (e0 + e1) + (e2 + e3);                                             \
                unsigned u0, u1;                                                         \
                asm("v_cvt_pk_bf16_f32 %0, %1, %2" : "=v"(u0) : "v"(e0), "v"(e1));       \
                asm("v_cvt_pk_bf16_f32 %0, %1, %2" : "=v"(u1) : "v"(e2), "v"(e3));       \
                pk[kb * 2] = u0; pk[kb * 2 + 1] = u1;                                    \
            }                                                                            \
            ls += __shfl_xor(ls, 16, 64);                                                \
            ls += __shfl_xor(ls, 32, 64);                                                \
            lrun[qs] += ls;                                                              \
            _Pragma("unroll") for (int kb = 0; kb < 4; ++kb) {                           \
                uint2 wv; wv.x = pk[kb * 2]; wv.y = pk[kb * 2 + 1];                      \
                *(uint2*)(Pw + qs * 2048 + l15 * 128 + ((kb * 32 + l4 * 8) ^ sw)) = wv;  \
            }                                                                            \
        }                                                                                \
        asm volatile("s_waitcnt lgkmcnt(0)" ::: "memory");                               \
        /* PV: A = P[q=l15][k contiguous], B = vf (col=l15=d) */                         \
        _Pragma("unroll") for (int qs = 0; qs < 2; ++qs)                                 \
            _Pragma("unroll") for (int ks = 0; ks < 2; ++ks) {                           \
                bf16x8 ap = *(const bf16x8*)(Pw + qs * 2048 + l15 * 128 +                \
                                             ((ks * 64 + l4 * 16) ^ sw));                \
                _Pragma("unroll") for (int dt = 0; dt < 4; ++dt)                         \
                    o[qs][dt] = mfma16(ap, vf[dt][ks], o[qs][dt]);                       \
            }                                                                            \
    }

    for (int kt2 = 0; kt2 < 16; ++kt2) {
        ATTN_STEP(2 * kt2, 0, 1)
        ATTN_STEP(2 * kt2 + 1, 1, 0)
    }
#undef ATTN_STEP

    // epilogue: lrun lives at lanes by l15; O rows are q=l4*4+r -> shfl
#pragma unroll
    for (int qs = 0; qs < 2; ++qs) {
#pragma unroll
        for (int r = 0; r < 4; ++r) {
            float lr = __shfl(lrun[qs], l4 * 4 + r, 64);
            float rl = 1.0f / lr;
            int q = q0 + qs * 16 + l4 * 4 + r;
            size_t base = ((size_t)b * 2048 + q) * 512 + h * 64;
#pragma unroll
            for (int dt = 0; dt < 4; ++dt)
                O[base + dt * 16 + l15] = (short)f2bf(o[qs][dt][r] * rl);
        }
    }
}

// ---------------- launcher ----------------
extern "C" void kernel_launch(void* const* d_in, const int* in_sizes, int n_in,
                              void* d_out, int out_size, void* d_ws, size_t ws_size,
                              hipStream_t stream) {
    const float* q  = (const float*)d_in[0];
    const float* k  = (const float*)d_in[1];
    const float* v  = (const float*)d_in[2];
    const int*   gm = (const int*)d_in[3];
    const float* Wq = (const float*)d_in[4];  const float* bq = (const float*)d_in[5];
    const float* Wk = (const float*)d_in[6];  const float* bk = (const float*)d_in[7];
    const float* Wv = (const float*)d_in[8];  const float* bv = (const float*)d_in[9];
    const float* Wo = (const float*)d_in[10]; const float* bo = (const float*)d_in[11];

    char* ws = (char*)d_ws;
    short* Xq  = (short*)(ws + 0);
    short* Xk  = (short*)(ws + 8388608);
    short* Xv  = (short*)(ws + 16777216);
    short* WqT = (short*)(ws + 25165824);
    short* WkT = (short*)(ws + 25690112);
    short* WvT = (short*)(ws + 26214400);
    short* WoT = (short*)(ws + 26738688);
    short* Qw  = (short*)(ws + 27262976);    // [b,h,tok,d]
    short* Kw  = (short*)(ws + 35651584);    // [b,h,tok,d]
    short* VTw = (short*)(ws + 44040192);    // [b,h,d,tok]
    short* AO  = (short*)(ws + 52428800);    // attn out [b,tok,h*64+d]
    unsigned long long* MP = (unsigned long long*)(ws + 60817408);

    cvt_x_kernel<<<dim3(4096, 3), 256, 0, stream>>>(q, k, v, Xq, Xk, Xv);
    cvt_wt_kernel<<<dim3(128, 4), 256, 0, stream>>>(Wq, Wk, Wv, Wo, WqT, WkT, WvT, WoT);
    pack_mask_kernel<<<dim3(2048), 256, 0, stream>>>(gm, MP);

    gemm_kernel<<<dim3(4, 64), 256, 0, stream>>>(Xq, WqT, bq, Qw, 0);
    gemm_kernel<<<dim3(4, 64), 256, 0, stream>>>(Xk, WkT, bk, Kw, 1);
    gemm_kernel<<<dim3(4, 64), 256, 0, stream>>>(Xv, WvT, bv, VTw, 2);

    attn_kernel<<<dim3(16, 8, 4), 256, 0, stream>>>(Qw, Kw, VTw, MP, AO);

    gemm_kernel<<<dim3(4, 64), 256, 0, stream>>>(AO, WoT, bo, (void*)d_out, 3);
}